// Round 2
// baseline (204.468 us; speedup 1.0000x reference)
//
#include <hip/hip_runtime.h>
#include <hip/hip_bf16.h>

// out[b, p, c, d, e] = Re{ exp(i * phi[b] * p) * (sr + i*si)[b, p, c, d, e] }
//                    = sr * cos(phi[b]*p) - si * sin(phi[b]*p)
// B=8, C=40; per-batch stride C^4 = 2,560,000; p-stride C^3 = 64,000.
// R1 post-mortem: out buffer is n floats (complex ref cast to float32 => real
// part). Keep an interleaved fallback branch on out_size, fully bounds-guarded.

#define CUTOFF 40
#define C3 (CUTOFF * CUTOFF * CUTOFF)          // 64000  (divisible by 4)
#define C4 (C3 * CUTOFF)                       // 2560000

// --- real-part-only kernel: one thread per 4 complex elements -------------
__global__ __launch_bounds__(256) void phase_shifter_real(
    const float* __restrict__ phi,
    const float* __restrict__ sr,
    const float* __restrict__ si,
    float* __restrict__ out,
    int n4)
{
    int i = blockIdx.x * blockDim.x + threadIdx.x;
    if (i >= n4) return;

    int base = i * 4;
    int b    = base / C4;
    int rem  = base - b * C4;
    int p    = rem / C3;              // all 4 elems share (b,p): C3 % 4 == 0

    float s, c;
    sincosf(phi[b] * (float)p, &s, &c);

    const float4 re = ((const float4*)sr)[i];
    const float4 im = ((const float4*)si)[i];

    float4 o;
    o.x = re.x * c - im.x * s;
    o.y = re.y * c - im.y * s;
    o.z = re.z * c - im.z * s;
    o.w = re.w * c - im.w * s;
    ((float4*)out)[i] = o;
}

// --- interleaved complex fallback (only if out_size >= 2*n) ---------------
__global__ __launch_bounds__(256) void phase_shifter_cplx(
    const float* __restrict__ phi,
    const float* __restrict__ sr,
    const float* __restrict__ si,
    float* __restrict__ out,
    int n4)
{
    int i = blockIdx.x * blockDim.x + threadIdx.x;
    if (i >= n4) return;

    int base = i * 4;
    int b    = base / C4;
    int rem  = base - b * C4;
    int p    = rem / C3;

    float s, c;
    sincosf(phi[b] * (float)p, &s, &c);

    const float4 re = ((const float4*)sr)[i];
    const float4 im = ((const float4*)si)[i];

    float4 o0, o1;
    o0.x = re.x * c - im.x * s;  o0.y = re.x * s + im.x * c;
    o0.z = re.y * c - im.y * s;  o0.w = re.y * s + im.y * c;
    o1.x = re.z * c - im.z * s;  o1.y = re.z * s + im.z * c;
    o1.z = re.w * c - im.w * s;  o1.w = re.w * s + im.w * c;

    float4* out4 = (float4*)out;
    out4[2 * i]     = o0;
    out4[2 * i + 1] = o1;
}

extern "C" void kernel_launch(void* const* d_in, const int* in_sizes, int n_in,
                              void* d_out, int out_size, void* d_ws, size_t ws_size,
                              hipStream_t stream) {
    const float* phi = (const float*)d_in[0];
    const float* sr  = (const float*)d_in[1];
    const float* si  = (const float*)d_in[2];
    float* out = (float*)d_out;

    int n  = in_sizes[1];     // 20,480,000 complex elements
    int n4 = n / 4;

    int block = 256;
    int grid  = (n4 + block - 1) / block;

    if (out_size >= 2 * n) {
        phase_shifter_cplx<<<grid, block, 0, stream>>>(phi, sr, si, out, n4);
    } else {
        phase_shifter_real<<<grid, block, 0, stream>>>(phi, sr, si, out, n4);
    }
}